// Round 12
// baseline (206.061 us; speedup 1.0000x reference)
//
#include <hip/hip_runtime.h>
#include <math.h>

#define NPTS 32768
#define DD 8
#define OO 20      // ORDER+1
#define PP 20
#define NCHAIN 7   // c=0: mean chain; c=1..6: variance moment k=c
#define NT 2       // point-tiles (32 pts each) per wave — amortizes A loads
#define GSTRIDE 10 // dwords per G record (40B)

typedef _Float16 half8 __attribute__((ext_vector_type(8)));
typedef __fp16 fp16x2 __attribute__((ext_vector_type(2)));
typedef float floatx16 __attribute__((ext_vector_type(16)));
typedef unsigned int u32;

#define AS1 __attribute__((address_space(1)))
#define AS3 __attribute__((address_space(3)))

// sigma: row permutation baked into A so that C-layout output == next B layout
// (swap rows 4..7 <-> 8..11; identity elsewhere)
__device__ __forceinline__ int sigma_row(int m) {
    return (m >= 4 && m < 12) ? (m ^ 12) : m;
}

// basis b_q = binom[q] t^q (1-t)^(19-q), fp32 (prep only)
__device__ __forceinline__ void basis20(float tv, float* g) {
    constexpr float binom[OO] = {
        1.f, 19.f, 171.f, 969.f, 3876.f, 11628.f, 27132.f, 50388.f, 75582.f,
        92378.f, 92378.f, 75582.f, 50388.f, 27132.f, 11628.f, 3876.f, 969.f,
        171.f, 19.f, 1.f};
    float a = tv, b = 1.f - tv, v = 1.f;
#pragma unroll
    for (int q = 0; q < OO; ++q) { g[q] = v; v *= a; }
    v = 1.f;
#pragma unroll
    for (int q = OO - 1; q >= 0; --q) { g[q] = g[q] * v * binom[q]; v *= b; }
}

// RTN pack of two f32 into f16x2 dword (prep only — accuracy over speed)
__device__ __forceinline__ unsigned pk2rtn(float a, float b) {
    union { _Float16 h[2]; unsigned u; } cv;
    cv.h[0] = (_Float16)a; cv.h[1] = (_Float16)b;
    return cv.u;
}

__device__ __forceinline__ unsigned pack_pk(float x, float y) {
    union { fp16x2 h; unsigned u; } cv;
    cv.h = __builtin_amdgcn_cvt_pkrtz(x, y);
    return cv.u;
}

__device__ __forceinline__ fp16x2 u2h(unsigned u) {
    union { unsigned u; fp16x2 h; } c; c.u = u; return c.h;
}
__device__ __forceinline__ unsigned h2u(fp16x2 h) {
    union { unsigned u; fp16x2 h; } c; c.h = h; return c.u;
}

// ---------------------------------------------------------------------------
// Prep (one launch, four ranges):
//   W0[c][p][q]  fp32 = c==0 ? exp(meanw0) : exp(2*meanw0 + c*varw0)
//   WA[c][i][p][frag][lane][j] f16 — MFMA A-fragment order:
//     element = Apad[m][k], m = lane&31, k = (lane>>5)*8 + frag*16 + j,
//     Apad[m][k] = (q=sigma(m))<20 && k<20 ? W_c[o=k][q] : 0
//     This makes global_load_lds's linear (lane*16B) LDS write == the exact
//     per-lane ds_read_b128 fragment layout (conflict-free, no swizzle).
//   G[d][n]: 10 dwords (40B) of f16x2 GATE records in per-lane layout
//     (gate^2 on the fly in chain; ws bytes cost harness re-poison time):
//     dwords 0..5 lo-half pairs: (g0,g1)(g2,g3)(g4,g5)(g6,g7)(g16,g17)(g18,g19)
//     dwords 6..9 hi-half pairs: (g8,g9)(g10,g11)(g12,g13)(g14,g15)
//     (hi-half's two tail dwords are logical zeros — supplied in-kernel as uz)
//   cnt[128] zeros — last-block reduction counters (one per blockIdx.x)
// ---------------------------------------------------------------------------
__global__ void prep_kernel(const float* __restrict__ X,
                            const float* __restrict__ meanw0,
                            const float* __restrict__ meanw,
                            const float* __restrict__ varw0,
                            const float* __restrict__ varw,
                            float* __restrict__ W0,
                            _Float16* __restrict__ WA,
                            unsigned* __restrict__ G,
                            unsigned* __restrict__ cnt) {
    int e = blockIdx.x * 256 + threadIdx.x;
    const int n0 = NCHAIN * PP * OO;                 // 2800
    const int nW = NCHAIN * (DD - 1) * PP * 32 * 32; // 1,003,520
    const int nG = NPTS * DD;                        // 262,144
    if (e < n0) {
        int q = e % OO;
        int rem = e / OO;
        int p = rem % PP;
        int c = rem / PP;
        float m = meanw0[p * OO + q];
        W0[e] = (c == 0) ? __expf(m) : __expf(2.f * m + (float)c * varw0[p * OO + q]);
    } else if (e < n0 + nW) {
        int idx = e - n0;
        int j = idx & 7; idx >>= 3;
        int l = idx & 63; idx >>= 6;
        int f = idx & 1; idx >>= 1;
        int p = idx % PP; idx /= PP;
        int i = idx % (DD - 1);
        int c = idx / (DD - 1);
        int m = l & 31;
        int k = (l >> 5) * 8 + f * 16 + j;
        int q = sigma_row(m);
        float v = 0.f;
        if (q < OO && k < OO) {
            int mi = ((i * PP + p) * OO + k) * OO + q;   // meanw[i][p][o=k][q']
            float mm = meanw[mi];
            v = (c == 0) ? __expf(mm) : __expf(2.f * mm + (float)c * varw[mi]);
        }
        WA[e - n0] = (_Float16)v;
    } else if (e < n0 + nW + nG) {
        int idx = e - n0 - nW;
        int n = idx & (NPTS - 1);
        int d = idx >> 15;
        float g[OO];
        basis20(X[(size_t)n * DD + d], g);
        // compose 10 dwords in named registers (no array pun); uint2 stores
        // (records are 40B-strided -> only 8B alignment guaranteed)
        uint2 o0, o1, o2, o3, o4;
        o0.x = pk2rtn(g[0], g[1]);
        o0.y = pk2rtn(g[2], g[3]);
        o1.x = pk2rtn(g[4], g[5]);
        o1.y = pk2rtn(g[6], g[7]);
        o2.x = pk2rtn(g[16], g[17]);
        o2.y = pk2rtn(g[18], g[19]);
        o3.x = pk2rtn(g[8], g[9]);
        o3.y = pk2rtn(g[10], g[11]);
        o4.x = pk2rtn(g[12], g[13]);
        o4.y = pk2rtn(g[14], g[15]);
        uint2* out = (uint2*)(G + (size_t)(d * NPTS + n) * GSTRIDE);
        out[0] = o0; out[1] = o1; out[2] = o2; out[3] = o3; out[4] = o4;
    } else if (e < n0 + nW + nG + 128) {
        cnt[e - n0 - nW - nG] = 0u;
    }
}

// ---------------------------------------------------------------------------
// One wave = one p x NT*32 points x all 7 chains. State st[tile][c][0..5] is
// the f16 B-layout activation. Sigma row-permutation of A makes the MFMA C
// output pack DIRECTLY into the same lane's next-step B dwords.
// A-matrices (14KB per i-step, shared by all 4 waves: same p) are staged
// block-wide into double-buffered LDS via global_load_lds, one step ahead;
// the hot loop reads them with conflict-free ds_read_b128 at lane*16.
// Epilogue: per-p partial stores; the 20th block per x-column (device-scope
// counter) reduces all 20 partials and writes out (bit-identical p-order to
// the old reduce_kernel). No separate reduce launch.
// NOTE (r4/r5/r10 lessons): live state needs ~120 VGPRs. (256,4)
// launch_bounds caps at 64 VGPR -> total spill (8x). "Persistent uint32x4 B0"
// variant: 128 VGPR + partial spill. Runtime p-loop (PG=5): 128 VGPR + 1.2GB
// scratch. Keep marshal unions, (256,2), one p per block.
// r9 lesson: 20-way-contended atomicAdd epilogue = ~24us idle. Partial+
// single-reducer is the proven scheme.
// ---------------------------------------------------------------------------
__global__ __launch_bounds__(256, 2) void chain_kernel(
    const int* __restrict__ perm,
    const float* __restrict__ W0, const _Float16* __restrict__ WA,
    const unsigned* __restrict__ G, float* __restrict__ partial,
    unsigned* __restrict__ cnt, float* __restrict__ out) {
    const int lane = threadIdx.x & 63;
    const int wv = threadIdx.x >> 6;
    const int nl = lane & 31;
    const bool hi = (lane >> 5) != 0;
    const int n0 = (blockIdx.x * 4 + wv) * (32 * NT);
    const int p = blockIdx.y;
    const int goffd = hi ? 6 : 0;   // dword offset of this half-lane's gates

    // [buf][c*1024 + frag*512 + lane*8] halves; 2 x 14336 B
    __shared__ __align__(16) _Float16 Alds[2][NCHAIN * 1024];
    __shared__ bool isLast;

    int dp[DD];
#pragma unroll
    for (int i = 0; i < DD; ++i) dp[i] = perm[p * DD + i];

    // opaque zero: perm values are 0..7, so uz == 0, but the compiler can't
    // prove it — kZero stays pinned instead of being re-emitted per MFMA.
    const unsigned uz = ((unsigned)dp[0]) >> 20;
    const float fz = __uint_as_float(uz);
    floatx16 kZero;
#pragma unroll
    for (int r = 0; r < 16; ++r) kZero[r] = fz;

    // ---- issue staging of i=1 A-matrices into buf0 (latency hidden by init)
    {
        const _Float16* wbase = WA + (size_t)p * 1024;  // [c][i=0][p]
#pragma unroll
        for (int u = wv; u < 2 * NCHAIN; u += 4) {
            int c = u >> 1, h = u & 1;
            const _Float16* src =
                wbase + (size_t)c * (DD - 1) * PP * 1024 + h * 512 + lane * 8;
            __builtin_amdgcn_global_load_lds(
                (const AS1 u32*)src, (AS3 u32*)&Alds[0][u * 512], 16, 0, 0);
        }
    }

    unsigned st[NT][NCHAIN][6];

    // ---- init: f0[k] = W0[c][p][k] * gate0[k] (f32, unpacked f16 gates) ----
    // (hi lanes: 3rd uint2 reads past the record — discarded via uz select;
    //  worst case lands in the partial region, still inside ws)
#pragma unroll
    for (int tile = 0; tile < NT; ++tile) {
        const uint2* rp = (const uint2*)(
            G + ((size_t)dp[0] * NPTS + (n0 + tile * 32 + nl)) * GSTRIDE + goffd);
        uint2 r0 = rp[0], r1 = rp[1], r2 = rp[2];
        unsigned gw[6] = {r0.x, r0.y, r1.x, r1.y,
                          hi ? uz : r2.x, hi ? uz : r2.y};
        float gcf[12], scf[12];
#pragma unroll
        for (int q = 0; q < 6; ++q) {
            fp16x2 gh = u2h(gw[q]);
            gcf[2 * q] = (float)gh.x; gcf[2 * q + 1] = (float)gh.y;
        }
#pragma unroll
        for (int r = 0; r < 12; ++r) scf[r] = gcf[r] * gcf[r];
#pragma unroll
        for (int c = 0; c < NCHAIN; ++c) {
            const float* w0r = W0 + (c * PP + p) * OO;
            float val[12];
#pragma unroll
            for (int r = 0; r < 8; ++r) {
                float ws = hi ? w0r[r + 8] : w0r[r];
                val[r] = ws * (c == 0 ? gcf[r] : scf[r]);
            }
#pragma unroll
            for (int r = 8; r < 12; ++r) {
                float ws = hi ? 0.f : w0r[r + 8];
                val[r] = ws * (c == 0 ? gcf[r] : scf[r]);
            }
#pragma unroll
            for (int e = 0; e < 6; ++e)
                st[tile][c][e] = pack_pk(val[2 * e], val[2 * e + 1]);
        }
    }

    const float coef[NCHAIN] = {0.f, 1.f, 0.5f, 1.f / 6.f, 1.f / 24.f,
                                1.f / 120.f, 1.f / 720.f};
    float sm[NT], sv[NT];
#pragma unroll
    for (int tile = 0; tile < NT; ++tile) { sm[tile] = 0.f; sv[tile] = 0.f; }

    __syncthreads();   // drains vmcnt → buf0 staged

#pragma unroll
    for (int i = 1; i < DD; ++i) {
        const int cur = (i - 1) & 1;

        // issue next step's staging into the other buffer (latency hides
        // under this step's compute; drained by the end-of-step barrier)
        if (i < DD - 1) {
            const _Float16* wbase = WA + (size_t)(i * PP + p) * 1024;  // [c][i][p]
#pragma unroll
            for (int u = wv; u < 2 * NCHAIN; u += 4) {
                int c = u >> 1, h = u & 1;
                const _Float16* src =
                    wbase + (size_t)c * (DD - 1) * PP * 1024 + h * 512 + lane * 8;
                __builtin_amdgcn_global_load_lds(
                    (const AS1 u32*)src, (AS3 u32*)&Alds[cur ^ 1][u * 512], 16, 0, 0);
            }
        }

        unsigned gw[NT][6], sw[NT][6];
#pragma unroll
        for (int tile = 0; tile < NT; ++tile) {
            const uint2* rp = (const uint2*)(
                G + ((size_t)dp[i] * NPTS + (n0 + tile * 32 + nl)) * GSTRIDE + goffd);
            uint2 r0 = rp[0], r1 = rp[1], r2 = rp[2];
            gw[tile][0] = r0.x; gw[tile][1] = r0.y;
            gw[tile][2] = r1.x; gw[tile][3] = r1.y;
            gw[tile][4] = hi ? uz : r2.x; gw[tile][5] = hi ? uz : r2.y;
        }
        if (i < DD - 1) {
            // gate^2 in f16 (hi tail dwords are 0 -> square stays 0)
#pragma unroll
            for (int tile = 0; tile < NT; ++tile)
#pragma unroll
                for (int e = 0; e < 6; ++e) {
                    fp16x2 gh = u2h(gw[tile][e]);
                    sw[tile][e] = h2u(gh * gh);
                }
        }

        // final step needs f32 gates for the accurate reduction
        float gcf[NT][12], scf[NT][12];
        if (i == DD - 1) {
#pragma unroll
            for (int tile = 0; tile < NT; ++tile) {
#pragma unroll
                for (int q = 0; q < 6; ++q) {
                    fp16x2 gh = u2h(gw[tile][q]);
                    gcf[tile][2 * q] = (float)gh.x; gcf[tile][2 * q + 1] = (float)gh.y;
                }
#pragma unroll
                for (int r = 0; r < 12; ++r)
                    scf[tile][r] = gcf[tile][r] * gcf[tile][r];
            }
        }

#pragma unroll
        for (int c = 0; c < NCHAIN; ++c) {
            // conflict-free fragment reads: lane*16B contiguous
            const _Float16* ab = &Alds[cur][c * 1024 + lane * 8];
            half8 A0 = *(const half8*)(ab);
            half8 A1 = *(const half8*)(ab + 512);

#pragma unroll
            for (int tile = 0; tile < NT; ++tile) {
                union { unsigned u[4]; half8 h; } B0, B1;
                B0.u[0] = st[tile][c][0]; B0.u[1] = st[tile][c][1];
                B0.u[2] = st[tile][c][2]; B0.u[3] = st[tile][c][3];
                B1.u[0] = st[tile][c][4]; B1.u[1] = st[tile][c][5];
                B1.u[2] = uz;             B1.u[3] = uz;  // k>=20: A cols are 0

                floatx16 acc;
                acc = __builtin_amdgcn_mfma_f32_32x32x16_f16(A0, B0.h, kZero, 0, 0, 0);
                acc = __builtin_amdgcn_mfma_f32_32x32x16_f16(A1, B1.h, acc, 0, 0, 0);

                if (i < DD - 1) {
                    // gate+pack in f16: 6 cvt_pkrtz + 6 v_pk_mul_f16
#pragma unroll
                    for (int e = 0; e < 6; ++e) {
                        fp16x2 pr = __builtin_amdgcn_cvt_pkrtz(acc[2 * e], acc[2 * e + 1]);
                        fp16x2 gv = u2h(c == 0 ? gw[tile][e] : sw[tile][e]);
                        st[tile][c][e] = h2u(pr * gv);
                    }
                } else {
                    float s = 0.f;
#pragma unroll
                    for (int r = 0; r < 12; ++r)
                        s += acc[r] * (c == 0 ? gcf[tile][r] : scf[tile][r]);
                    if (c == 0) sm[tile] = s;
                    else        sv[tile] += coef[c] * s;
                }
            }
        }

        if (i < DD - 1) __syncthreads();  // staging done + all ds_reads done
    }

    // ---- epilogue: combine half-waves, write per-p partials ----
#pragma unroll
    for (int tile = 0; tile < NT; ++tile) {
        float m = sm[tile] + __shfl_xor(sm[tile], 32, 64);
        float v = sv[tile] + __shfl_xor(sv[tile], 32, 64);
        if (lane < 32) {
            partial[(size_t)p * NPTS + n0 + tile * 32 + nl] = m;
            partial[(size_t)(PP + p) * NPTS + n0 + tile * 32 + nl] = v;
        }
    }

    // ---- last block per x-column reduces all PP partials -> out ----
    __syncthreads();                 // all partial stores complete (vmcnt 0)
    if (threadIdx.x == 0) {
        __threadfence();             // release: publish partials device-wide
        unsigned old = atomicAdd(&cnt[blockIdx.x], 1u);
        isLast = (old == PP - 1);
    }
    __syncthreads();
    if (isLast) {
        __threadfence();             // acquire: see other blocks' partials
        int n = blockIdx.x * 256 + threadIdx.x;
        float m = 0.f, v = 0.f;
#pragma unroll
        for (int p2 = 0; p2 < PP; ++p2) {
            m += partial[(size_t)p2 * NPTS + n];
            v += partial[(size_t)(PP + p2) * NPTS + n];
        }
        out[2 * n] = m;
        out[2 * n + 1] = v;
    }
}

extern "C" void kernel_launch(void* const* d_in, const int* in_sizes, int n_in,
                              void* d_out, int out_size, void* d_ws, size_t ws_size,
                              hipStream_t stream) {
    const float* X      = (const float*)d_in[0];
    const int*   perm   = (const int*)d_in[1];
    const float* meanw0 = (const float*)d_in[2];
    const float* meanw  = (const float*)d_in[3];
    const float* varw0  = (const float*)d_in[4];
    const float* varw   = (const float*)d_in[5];
    float* out = (float*)d_out;

    // workspace: [W0: 11,200B][WA: 2,007,040B][G: 10,485,760B]
    //            [partial: 5,242,880B][cnt: 512B]   total 17,747,392B
    // (ws bytes are re-poisoned by the harness every iteration — keep small;
    //  32.4->14.6MB cut the non-kernel gap 70.6->37.8us, r6->r9)
    float*     W0      = (float*)d_ws;
    _Float16*  WA      = (_Float16*)((char*)d_ws + 11200);
    unsigned*  G       = (unsigned*)((char*)d_ws + 11200 + 2007040);
    float*     partial = (float*)((char*)d_ws + 11200 + 2007040 + 10485760);
    unsigned*  cnt     = (unsigned*)((char*)d_ws + 11200 + 2007040 + 10485760 + 5242880);

    int prep_n = NCHAIN * PP * OO + NCHAIN * (DD - 1) * PP * 32 * 32
               + NPTS * DD + 128;
    hipLaunchKernelGGL(prep_kernel, dim3((prep_n + 255) / 256), dim3(256), 0,
                       stream, X, meanw0, meanw, varw0, varw, W0, WA, G, cnt);

    dim3 grid(NPTS / (128 * NT), PP);  // 4 waves/block, NT*32 pts/wave
    hipLaunchKernelGGL(chain_kernel, grid, dim3(256), 0, stream,
                       perm, W0, WA, G, partial, cnt, out);
}

// Round 13
// 144.129 us; speedup vs baseline: 1.4297x; 1.4297x over previous
//
#include <hip/hip_runtime.h>
#include <math.h>

#define NPTS 32768
#define DD 8
#define OO 20      // ORDER+1
#define PP 20
#define NCHAIN 7   // c=0: mean chain; c=1..6: variance moment k=c
#define NT 2       // point-tiles (32 pts each) per wave — amortizes A loads
#define GSTRIDE 10 // dwords per G record (40B)
#define NSLAB 8    // atomic slabs; contention = ceil(PP/NSLAB) = 3-way max

typedef _Float16 half8 __attribute__((ext_vector_type(8)));
typedef __fp16 fp16x2 __attribute__((ext_vector_type(2)));
typedef float floatx16 __attribute__((ext_vector_type(16)));
typedef unsigned int u32;

#define AS1 __attribute__((address_space(1)))
#define AS3 __attribute__((address_space(3)))

// sigma: row permutation baked into A so that C-layout output == next B layout
// (swap rows 4..7 <-> 8..11; identity elsewhere)
__device__ __forceinline__ int sigma_row(int m) {
    return (m >= 4 && m < 12) ? (m ^ 12) : m;
}

// basis b_q = binom[q] t^q (1-t)^(19-q), fp32 (prep only)
__device__ __forceinline__ void basis20(float tv, float* g) {
    constexpr float binom[OO] = {
        1.f, 19.f, 171.f, 969.f, 3876.f, 11628.f, 27132.f, 50388.f, 75582.f,
        92378.f, 92378.f, 75582.f, 50388.f, 27132.f, 11628.f, 3876.f, 969.f,
        171.f, 19.f, 1.f};
    float a = tv, b = 1.f - tv, v = 1.f;
#pragma unroll
    for (int q = 0; q < OO; ++q) { g[q] = v; v *= a; }
    v = 1.f;
#pragma unroll
    for (int q = OO - 1; q >= 0; --q) { g[q] = g[q] * v * binom[q]; v *= b; }
}

// RTN pack of two f32 into f16x2 dword (prep only — accuracy over speed)
__device__ __forceinline__ unsigned pk2rtn(float a, float b) {
    union { _Float16 h[2]; unsigned u; } cv;
    cv.h[0] = (_Float16)a; cv.h[1] = (_Float16)b;
    return cv.u;
}

__device__ __forceinline__ unsigned pack_pk(float x, float y) {
    union { fp16x2 h; unsigned u; } cv;
    cv.h = __builtin_amdgcn_cvt_pkrtz(x, y);
    return cv.u;
}

__device__ __forceinline__ fp16x2 u2h(unsigned u) {
    union { unsigned u; fp16x2 h; } c; c.u = u; return c.h;
}
__device__ __forceinline__ unsigned h2u(fp16x2 h) {
    union { unsigned u; fp16x2 h; } c; c.h = h; return c.u;
}

// ---------------------------------------------------------------------------
// Prep (one launch, four ranges):
//   W0[c][p][q]  fp32 = c==0 ? exp(meanw0) : exp(2*meanw0 + c*varw0)
//   WA[c][i][p][frag][lane][j] f16 — MFMA A-fragment order:
//     element = Apad[m][k], m = lane&31, k = (lane>>5)*8 + frag*16 + j,
//     Apad[m][k] = (q=sigma(m))<20 && k<20 ? W_c[o=k][q] : 0
//     This makes global_load_lds's linear (lane*16B) LDS write == the exact
//     per-lane ds_read_b128 fragment layout (conflict-free, no swizzle).
//   G[d][n]: 10 dwords (40B) of f16x2 GATE records in per-lane layout
//     (gate^2 on the fly in chain; ws bytes cost harness re-poison time):
//     dwords 0..5 lo-half pairs: (g0,g1)(g2,g3)(g4,g5)(g6,g7)(g16,g17)(g18,g19)
//     dwords 6..9 hi-half pairs: (g8,g9)(g10,g11)(g12,g13)(g14,g15)
//     (hi-half's two tail dwords are logical zeros — supplied in-kernel as uz)
//   slab[NSLAB][2][NPTS] f32 zeros — low-contention atomic accumulators
// ---------------------------------------------------------------------------
__global__ void prep_kernel(const float* __restrict__ X,
                            const float* __restrict__ meanw0,
                            const float* __restrict__ meanw,
                            const float* __restrict__ varw0,
                            const float* __restrict__ varw,
                            float* __restrict__ W0,
                            _Float16* __restrict__ WA,
                            unsigned* __restrict__ G,
                            uint4* __restrict__ slabz) {
    int e = blockIdx.x * 256 + threadIdx.x;
    const int n0 = NCHAIN * PP * OO;                 // 2800
    const int nW = NCHAIN * (DD - 1) * PP * 32 * 32; // 1,003,520
    const int nG = NPTS * DD;                        // 262,144
    const int nZ = NSLAB * 2 * NPTS / 4;             // 131,072 uint4 stores
    if (e < n0) {
        int q = e % OO;
        int rem = e / OO;
        int p = rem % PP;
        int c = rem / PP;
        float m = meanw0[p * OO + q];
        W0[e] = (c == 0) ? __expf(m) : __expf(2.f * m + (float)c * varw0[p * OO + q]);
    } else if (e < n0 + nW) {
        int idx = e - n0;
        int j = idx & 7; idx >>= 3;
        int l = idx & 63; idx >>= 6;
        int f = idx & 1; idx >>= 1;
        int p = idx % PP; idx /= PP;
        int i = idx % (DD - 1);
        int c = idx / (DD - 1);
        int m = l & 31;
        int k = (l >> 5) * 8 + f * 16 + j;
        int q = sigma_row(m);
        float v = 0.f;
        if (q < OO && k < OO) {
            int mi = ((i * PP + p) * OO + k) * OO + q;   // meanw[i][p][o=k][q']
            float mm = meanw[mi];
            v = (c == 0) ? __expf(mm) : __expf(2.f * mm + (float)c * varw[mi]);
        }
        WA[e - n0] = (_Float16)v;
    } else if (e < n0 + nW + nG) {
        int idx = e - n0 - nW;
        int n = idx & (NPTS - 1);
        int d = idx >> 15;
        float g[OO];
        basis20(X[(size_t)n * DD + d], g);
        // compose 10 dwords in named registers (no array pun); uint2 stores
        // (records are 40B-strided -> only 8B alignment guaranteed)
        uint2 o0, o1, o2, o3, o4;
        o0.x = pk2rtn(g[0], g[1]);
        o0.y = pk2rtn(g[2], g[3]);
        o1.x = pk2rtn(g[4], g[5]);
        o1.y = pk2rtn(g[6], g[7]);
        o2.x = pk2rtn(g[16], g[17]);
        o2.y = pk2rtn(g[18], g[19]);
        o3.x = pk2rtn(g[8], g[9]);
        o3.y = pk2rtn(g[10], g[11]);
        o4.x = pk2rtn(g[12], g[13]);
        o4.y = pk2rtn(g[14], g[15]);
        uint2* out = (uint2*)(G + (size_t)(d * NPTS + n) * GSTRIDE);
        out[0] = o0; out[1] = o1; out[2] = o2; out[3] = o3; out[4] = o4;
    } else if (e < n0 + nW + nG + nZ) {
        slabz[e - n0 - nW - nG] = make_uint4(0u, 0u, 0u, 0u);
    }
}

// ---------------------------------------------------------------------------
// One wave = one p x NT*32 points x all 7 chains. State st[tile][c][0..5] is
// the f16 B-layout activation. Sigma row-permutation of A makes the MFMA C
// output pack DIRECTLY into the same lane's next-step B dwords.
// A-matrices (14KB per i-step, shared by all 4 waves: same p) are staged
// block-wide into double-buffered LDS via global_load_lds, one step ahead;
// the hot loop reads them with conflict-free ds_read_b128 at lane*16.
// Epilogue: atomicAdd into slab[p&7] — <=3-way contention (r9's 20-way into
// out cost ~24us idle; r12's fence-fused reduce cost ~65us via L2 writebacks).
// NOTE (r4/r5/r10 lessons): live state needs ~120 VGPRs. (256,4)
// launch_bounds caps at 64 VGPR -> total spill (8x). "Persistent uint32x4 B0"
// variant: 128 VGPR + partial spill. Runtime p-loop (PG=5): 128 VGPR + 1.2GB
// scratch. Keep marshal unions, (256,2), one p per block.
// ---------------------------------------------------------------------------
__global__ __launch_bounds__(256, 2) void chain_kernel(
    const int* __restrict__ perm,
    const float* __restrict__ W0, const _Float16* __restrict__ WA,
    const unsigned* __restrict__ G, float* __restrict__ slab) {
    const int lane = threadIdx.x & 63;
    const int wv = threadIdx.x >> 6;
    const int nl = lane & 31;
    const bool hi = (lane >> 5) != 0;
    const int n0 = (blockIdx.x * 4 + wv) * (32 * NT);
    const int p = blockIdx.y;
    const int goffd = hi ? 6 : 0;   // dword offset of this half-lane's gates

    // [buf][c*1024 + frag*512 + lane*8] halves; 2 x 14336 B
    __shared__ __align__(16) _Float16 Alds[2][NCHAIN * 1024];

    int dp[DD];
#pragma unroll
    for (int i = 0; i < DD; ++i) dp[i] = perm[p * DD + i];

    // opaque zero: perm values are 0..7, so uz == 0, but the compiler can't
    // prove it — kZero stays pinned instead of being re-emitted per MFMA.
    const unsigned uz = ((unsigned)dp[0]) >> 20;
    const float fz = __uint_as_float(uz);
    floatx16 kZero;
#pragma unroll
    for (int r = 0; r < 16; ++r) kZero[r] = fz;

    // ---- issue staging of i=1 A-matrices into buf0 (latency hidden by init)
    {
        const _Float16* wbase = WA + (size_t)p * 1024;  // [c][i=0][p]
#pragma unroll
        for (int u = wv; u < 2 * NCHAIN; u += 4) {
            int c = u >> 1, h = u & 1;
            const _Float16* src =
                wbase + (size_t)c * (DD - 1) * PP * 1024 + h * 512 + lane * 8;
            __builtin_amdgcn_global_load_lds(
                (const AS1 u32*)src, (AS3 u32*)&Alds[0][u * 512], 16, 0, 0);
        }
    }

    unsigned st[NT][NCHAIN][6];

    // ---- init: f0[k] = W0[c][p][k] * gate0[k] (f32, unpacked f16 gates) ----
    // (hi lanes: 3rd uint2 reads past the record — discarded via uz select;
    //  worst case lands in the slab region, still inside ws)
#pragma unroll
    for (int tile = 0; tile < NT; ++tile) {
        const uint2* rp = (const uint2*)(
            G + ((size_t)dp[0] * NPTS + (n0 + tile * 32 + nl)) * GSTRIDE + goffd);
        uint2 r0 = rp[0], r1 = rp[1], r2 = rp[2];
        unsigned gw[6] = {r0.x, r0.y, r1.x, r1.y,
                          hi ? uz : r2.x, hi ? uz : r2.y};
        float gcf[12], scf[12];
#pragma unroll
        for (int q = 0; q < 6; ++q) {
            fp16x2 gh = u2h(gw[q]);
            gcf[2 * q] = (float)gh.x; gcf[2 * q + 1] = (float)gh.y;
        }
#pragma unroll
        for (int r = 0; r < 12; ++r) scf[r] = gcf[r] * gcf[r];
#pragma unroll
        for (int c = 0; c < NCHAIN; ++c) {
            const float* w0r = W0 + (c * PP + p) * OO;
            float val[12];
#pragma unroll
            for (int r = 0; r < 8; ++r) {
                float ws = hi ? w0r[r + 8] : w0r[r];
                val[r] = ws * (c == 0 ? gcf[r] : scf[r]);
            }
#pragma unroll
            for (int r = 8; r < 12; ++r) {
                float ws = hi ? 0.f : w0r[r + 8];
                val[r] = ws * (c == 0 ? gcf[r] : scf[r]);
            }
#pragma unroll
            for (int e = 0; e < 6; ++e)
                st[tile][c][e] = pack_pk(val[2 * e], val[2 * e + 1]);
        }
    }

    const float coef[NCHAIN] = {0.f, 1.f, 0.5f, 1.f / 6.f, 1.f / 24.f,
                                1.f / 120.f, 1.f / 720.f};
    float sm[NT], sv[NT];
#pragma unroll
    for (int tile = 0; tile < NT; ++tile) { sm[tile] = 0.f; sv[tile] = 0.f; }

    __syncthreads();   // drains vmcnt → buf0 staged

#pragma unroll
    for (int i = 1; i < DD; ++i) {
        const int cur = (i - 1) & 1;

        // issue next step's staging into the other buffer (latency hides
        // under this step's compute; drained by the end-of-step barrier)
        if (i < DD - 1) {
            const _Float16* wbase = WA + (size_t)(i * PP + p) * 1024;  // [c][i][p]
#pragma unroll
            for (int u = wv; u < 2 * NCHAIN; u += 4) {
                int c = u >> 1, h = u & 1;
                const _Float16* src =
                    wbase + (size_t)c * (DD - 1) * PP * 1024 + h * 512 + lane * 8;
                __builtin_amdgcn_global_load_lds(
                    (const AS1 u32*)src, (AS3 u32*)&Alds[cur ^ 1][u * 512], 16, 0, 0);
            }
        }

        unsigned gw[NT][6], sw[NT][6];
#pragma unroll
        for (int tile = 0; tile < NT; ++tile) {
            const uint2* rp = (const uint2*)(
                G + ((size_t)dp[i] * NPTS + (n0 + tile * 32 + nl)) * GSTRIDE + goffd);
            uint2 r0 = rp[0], r1 = rp[1], r2 = rp[2];
            gw[tile][0] = r0.x; gw[tile][1] = r0.y;
            gw[tile][2] = r1.x; gw[tile][3] = r1.y;
            gw[tile][4] = hi ? uz : r2.x; gw[tile][5] = hi ? uz : r2.y;
        }
        if (i < DD - 1) {
            // gate^2 in f16 (hi tail dwords are 0 -> square stays 0)
#pragma unroll
            for (int tile = 0; tile < NT; ++tile)
#pragma unroll
                for (int e = 0; e < 6; ++e) {
                    fp16x2 gh = u2h(gw[tile][e]);
                    sw[tile][e] = h2u(gh * gh);
                }
        }

        // final step needs f32 gates for the accurate reduction
        float gcf[NT][12], scf[NT][12];
        if (i == DD - 1) {
#pragma unroll
            for (int tile = 0; tile < NT; ++tile) {
#pragma unroll
                for (int q = 0; q < 6; ++q) {
                    fp16x2 gh = u2h(gw[tile][q]);
                    gcf[tile][2 * q] = (float)gh.x; gcf[tile][2 * q + 1] = (float)gh.y;
                }
#pragma unroll
                for (int r = 0; r < 12; ++r)
                    scf[tile][r] = gcf[tile][r] * gcf[tile][r];
            }
        }

#pragma unroll
        for (int c = 0; c < NCHAIN; ++c) {
            // conflict-free fragment reads: lane*16B contiguous
            const _Float16* ab = &Alds[cur][c * 1024 + lane * 8];
            half8 A0 = *(const half8*)(ab);
            half8 A1 = *(const half8*)(ab + 512);

#pragma unroll
            for (int tile = 0; tile < NT; ++tile) {
                union { unsigned u[4]; half8 h; } B0, B1;
                B0.u[0] = st[tile][c][0]; B0.u[1] = st[tile][c][1];
                B0.u[2] = st[tile][c][2]; B0.u[3] = st[tile][c][3];
                B1.u[0] = st[tile][c][4]; B1.u[1] = st[tile][c][5];
                B1.u[2] = uz;             B1.u[3] = uz;  // k>=20: A cols are 0

                floatx16 acc;
                acc = __builtin_amdgcn_mfma_f32_32x32x16_f16(A0, B0.h, kZero, 0, 0, 0);
                acc = __builtin_amdgcn_mfma_f32_32x32x16_f16(A1, B1.h, acc, 0, 0, 0);

                if (i < DD - 1) {
                    // gate+pack in f16: 6 cvt_pkrtz + 6 v_pk_mul_f16
#pragma unroll
                    for (int e = 0; e < 6; ++e) {
                        fp16x2 pr = __builtin_amdgcn_cvt_pkrtz(acc[2 * e], acc[2 * e + 1]);
                        fp16x2 gv = u2h(c == 0 ? gw[tile][e] : sw[tile][e]);
                        st[tile][c][e] = h2u(pr * gv);
                    }
                } else {
                    float s = 0.f;
#pragma unroll
                    for (int r = 0; r < 12; ++r)
                        s += acc[r] * (c == 0 ? gcf[tile][r] : scf[tile][r]);
                    if (c == 0) sm[tile] = s;
                    else        sv[tile] += coef[c] * s;
                }
            }
        }

        if (i < DD - 1) __syncthreads();  // staging done + all ds_reads done
    }

    // ---- epilogue: combine half-waves, atomicAdd into p-striped slab ----
    const int sl = p & (NSLAB - 1);
#pragma unroll
    for (int tile = 0; tile < NT; ++tile) {
        float m = sm[tile] + __shfl_xor(sm[tile], 32, 64);
        float v = sv[tile] + __shfl_xor(sv[tile], 32, 64);
        if (lane < 32) {
            int n = n0 + tile * 32 + nl;
            atomicAdd(&slab[(size_t)(2 * sl) * NPTS + n], m);
            atomicAdd(&slab[(size_t)(2 * sl + 1) * NPTS + n], v);
        }
    }
}

// ---------------------------------------------------------------------------
// Reduce over slabs: out[n][0] = sum_s slab[s][0][n]; out[n][1] likewise
// ---------------------------------------------------------------------------
__global__ void reduce_kernel(const float* __restrict__ slab,
                              float* __restrict__ out) {
    int n = blockIdx.x * 256 + threadIdx.x;
    float m = 0.f, v = 0.f;
#pragma unroll
    for (int s = 0; s < NSLAB; ++s) {
        m += slab[(size_t)(2 * s) * NPTS + n];
        v += slab[(size_t)(2 * s + 1) * NPTS + n];
    }
    out[2 * n] = m;
    out[2 * n + 1] = v;
}

extern "C" void kernel_launch(void* const* d_in, const int* in_sizes, int n_in,
                              void* d_out, int out_size, void* d_ws, size_t ws_size,
                              hipStream_t stream) {
    const float* X      = (const float*)d_in[0];
    const int*   perm   = (const int*)d_in[1];
    const float* meanw0 = (const float*)d_in[2];
    const float* meanw  = (const float*)d_in[3];
    const float* varw0  = (const float*)d_in[4];
    const float* varw   = (const float*)d_in[5];
    float* out = (float*)d_out;

    // workspace: [W0: 11,200B][WA: 2,007,040B][G: 10,485,760B]
    //            [slab: 2,097,152B]   total 14,601,152B
    // (ws bytes are re-poisoned by the harness every iteration — keep small;
    //  32.4->14.6MB cut the non-kernel gap 70.6->37.8us, r6->r9)
    float*     W0   = (float*)d_ws;
    _Float16*  WA   = (_Float16*)((char*)d_ws + 11200);
    unsigned*  G    = (unsigned*)((char*)d_ws + 11200 + 2007040);
    float*     slab = (float*)((char*)d_ws + 11200 + 2007040 + 10485760);

    int prep_n = NCHAIN * PP * OO + NCHAIN * (DD - 1) * PP * 32 * 32
               + NPTS * DD + NSLAB * 2 * NPTS / 4;
    hipLaunchKernelGGL(prep_kernel, dim3((prep_n + 255) / 256), dim3(256), 0,
                       stream, X, meanw0, meanw, varw0, varw, W0, WA, G,
                       (uint4*)slab);

    dim3 grid(NPTS / (128 * NT), PP);  // 4 waves/block, NT*32 pts/wave
    hipLaunchKernelGGL(chain_kernel, grid, dim3(256), 0, stream,
                       perm, W0, WA, G, slab);

    hipLaunchKernelGGL(reduce_kernel, dim3(NPTS / 256), dim3(256), 0, stream,
                       slab, out);
}